// Round 15
// baseline (247.307 us; speedup 1.0000x reference)
//
#include <hip/hip_runtime.h>
#include <stdint.h>

typedef __attribute__((ext_vector_type(8))) short bf16x8;
typedef __attribute__((ext_vector_type(16))) float f32x16;
typedef __attribute__((ext_vector_type(4))) float f32x4;
typedef __attribute__((ext_vector_type(4))) unsigned short u16x4;

#define NB 32
#define HH 128
#define WW 128
#define CI 128
#define CO 128
#define HO 126
#define WO 126
#define TH 16
#define TW 16
#define PHh 18
#define PWw 18
#define NROW (PHh * PWw)   // 324 patch rows
#define RSTR 72            // shorts per LDS row (144 B): affine immediates only
#define RSTRB 144

__device__ __forceinline__ unsigned short f2bf(float f) {
  union { float f; unsigned u; } x; x.f = f;
  unsigned u = x.u;
  u += 0x7FFFu + ((u >> 16) & 1u);   // RNE round to bf16
  return (unsigned short)(u >> 16);
}

// cvt_pk_bf16_f32: RNE, packs 2 f32 -> 2 bf16 in one VALU op (no builtin on gfx950)
__device__ __forceinline__ unsigned cvtpk_bf16(float a, float b) {
  unsigned r;
  asm("v_cvt_pk_bf16_f32 %0, %1, %2" : "=v"(r) : "v"(a), "v"(b));
  return r;  // low16 = bf16(a), high16 = bf16(b)
}

// prep for 32x32x16 MFMA: [b,p][ci][co] f32 -> bf16 slices for the B operand.
//   kgg = ci>>4 (0..7), slice sl = (kgg>>2)*36 + p*4 + (kgg&3), 2048 shorts:
//   addr = co*16 + (ci&15). Wave frag (co-group g of 32): lane l reads 8
//   shorts at g*512 + (l&31)*16 + (l>>5)*8  ->  B[k=(l>>5)*8+e][co=g*32+(l&31)].
__global__ void prep_kt(const float* __restrict__ kin, unsigned short* __restrict__ ktr) {
  __shared__ unsigned short t[CI * CO];  // 32 KB
  int bp = blockIdx.x;  // b*9+p, 0..287
  int b = bp / 9, p = bp % 9;
  const float* src = kin + (size_t)bp * (CI * CO);
  unsigned short* dstb = ktr + (size_t)b * (9 * CI * CO);
  for (int i = threadIdx.x; i < CI * CO / 4; i += blockDim.x) {
    f32x4 v = *(const f32x4*)(src + i * 4);
    u16x4 o;
    o.x = f2bf(v.x); o.y = f2bf(v.y); o.z = f2bf(v.z); o.w = f2bf(v.w);
    *(u16x4*)&t[i * 4] = o;
  }
  __syncthreads();
  for (int u = threadIdx.x; u < 2048; u += blockDim.x) {  // one bf16x8 each
    int kgg = u >> 8;                  // ci group of 16 (0..7)
    int j = u & 255;                   // within: 128 co x 2 ci8-halves
    int co = j >> 1, ci8 = (j & 1) * 8;
    bf16x8 v;
#pragma unroll
    for (int e = 0; e < 8; ++e) v[e] = t[(kgg * 16 + ci8 + e) * CO + co];
    int sl = (kgg >> 2) * 36 + p * 4 + (kgg & 3);
    *(bf16x8*)&dstb[(size_t)sl * 2048 + co * 16 + ci8] = v;
  }
}

// naive fallback (only if ws_size too small — not expected on this harness)
__global__ void conv_naive(const float* __restrict__ X, const float* __restrict__ Kf,
                           float* __restrict__ out) {
  int idx = blockIdx.x * blockDim.x + threadIdx.x;           // over B*HO*WO*CO
  if (idx >= NB * HO * WO * CO) return;
  int co = idx & 127, t = idx >> 7;
  int wp = t % WO; t /= WO;
  int hp = t % HO; int b = t / HO;
  const float* xb = X + (size_t)b * HH * WW * CI;
  const float* kb = Kf + (size_t)b * 9 * CI * CO;
  float s = 0.f;
  for (int p = 0; p < 9; ++p) {
    int kh = p / 3, kw = p % 3;
    const float* xr = xb + ((size_t)(hp + kh) * WW + (wp + kw)) * CI;
    const float* kr = kb + (size_t)p * CI * CO + co;
    for (int ci = 0; ci < CI; ++ci) s += xr[ci] * kr[(size_t)ci * CO];
  }
  out[idx] = s;
}

// R15: 32x32x16 MFMA on the R4 skeleton. Cross-variant accounting (R4..R14)
// shows time is ~1500 cyc per wave x 16 MFMA(16x16x32) unit INVARIANT to
// operand bytes, staging, prefetch depth, occupancy -> the wall scales with
// MFMA instruction count, not operand feeds. 32x32x16 halves instructions
// (and operand bytes) per FLOP: wave slab = 2 m-tiles (M=32 = 2h x 16w) x
// 2 co-groups (64co), 4 MFMA/round, 36 rounds/ci-half. acc 4 x f32x16 = 64.
// (512,3): ~170-reg budget, 3 blocks/CU = 6 waves/SIMD (LDS 140 KB).
__global__ __launch_bounds__(512, 3) void conv_main(
    const float* __restrict__ X, const unsigned short* __restrict__ Kt,
    float* __restrict__ out) {
  __shared__ unsigned short lds_a[NROW * RSTR];  // 46656 B -> 3 blocks/CU

  const int tid = threadIdx.x;
  const int lane = tid & 63;
  const int wid = tid >> 6;            // 8 waves, 4 (h) x 2 (co)
  const int wr = wid >> 1, wc = wid & 1;

  // XCD-clustered block swizzle: 4 whole batches per XCD (L2-resident B).
  const int l = blockIdx.x;            // 0..2047
  const int xcd = l & 7, j = l >> 3;   // j: 0..255
  const int b = xcd * 4 + (j >> 6);    // 4 batches per XCD
  const int t = j & 63;                // tile within batch (8x8 of 16x16)
  const int ht = t >> 3, wt = t & 7;
  const int h0 = ht * TH, w0 = wt * TW;

  const float* xb = X + (size_t)b * HH * WW * CI;

  // ---- stage (R4-identical): slot s = tid + k*512; row = (tid>>4) + 32k ----
  const int ci4 = tid & 15;
  const int row0 = tid >> 4;                  // 0..31
  const int hi0 = (row0 >= PWw) ? 1 : 0;
  const int wi0 = row0 - hi0 * PWw;
  char* const dst0 = (char*)lds_a + row0 * RSTRB + ci4 * 8;

  auto stageA = [&](int ch) {
    int h = hi0, w = wi0;
    const float* srcb = xb + ch * 64 + ci4 * 4;
#pragma unroll
    for (int k = 0; k < 11; ++k) {            // 10 full rounds + 4-row tail
      if (k < 10 || tid < 64) {
        int gh = h0 + h, gw = w0 + w;
        bool ok = (gh | gw) < HH;             // gh<128 && gw<128 (both <256)
        const float* src = srcb + ((size_t)(((gh & 127) << 7) + (gw & 127)) << 7);
        f32x4 v = *(const f32x4*)src;
        uint2 o;
        o.x = ok ? cvtpk_bf16(v.x, v.y) : 0u;
        o.y = ok ? cvtpk_bf16(v.z, v.w) : 0u;
        *(uint2*)(dst0 + k * (32 * RSTRB)) = o;  // offset folds into ds imm
      }
      w += 14;                                // advance 32 rows: h+=1, w+=14 wrap
      int wrap = (w >= PWw) ? 1 : 0;
      h += 1 + wrap;
      w -= wrap ? PWw : 0;
    }
  };

  // ---- A fragments (32x32x16): lane row = lane&31 -> (h_sub, w), k-half =
  // lane>>5. byte base covers (wr, h_sub, w, khalf); per (mt,kh,kw,kg) all
  // compile-time immediates (anti-spill invariant).
  const int hsub = (lane >> 4) & 1, wl = lane & 15, kk = lane >> 5;
  const int abase = ((wr * 4 + hsub) * PWw + wl) * RSTR + kk * 8;  // shorts

  // ---- B: ring-of-3, slices are round-consecutive (p*4+kg) ----
  const unsigned short* ktb = Kt + (size_t)b * (9 * CI * CO) +
                              (wc * 2) * 512 + (lane & 31) * 16 + kk * 8;
  bf16x8 Hf[3][2];
  auto loadB = [&](bf16x8 (&dst)[2], int sl) {
    dst[0] = *(const bf16x8*)(ktb + (size_t)sl * 2048);
    dst[1] = *(const bf16x8*)(ktb + (size_t)sl * 2048 + 512);
  };

  f32x16 zero16 = {0.f, 0.f, 0.f, 0.f, 0.f, 0.f, 0.f, 0.f,
                   0.f, 0.f, 0.f, 0.f, 0.f, 0.f, 0.f, 0.f};
  f32x16 acc[2][2];                    // 64 regs
#pragma unroll
  for (int mt = 0; mt < 2; ++mt)
#pragma unroll
    for (int g = 0; g < 2; ++g) acc[mt][g] = zero16;

#pragma unroll 1
  for (int ch = 0; ch < 2; ++ch) {
    if (ch) __syncthreads();           // all waves done reading previous half
    loadB(Hf[0], ch * 36);             // first two slices fly during staging
    loadB(Hf[1], ch * 36 + 1);
    stageA(ch);
    __syncthreads();                   // lds_a ready

    // 36 rounds: kh x kw x kg, all compile-time; 4 MFMA-32 per round.
#pragma unroll
    for (int kh = 0; kh < 3; ++kh) {
#pragma unroll
      for (int kw = 0; kw < 3; ++kw) {
#pragma unroll
        for (int kg = 0; kg < 4; ++kg) {
          const int r = kh * 12 + kw * 4 + kg;
          // B prefetch distance 2 (ring-of-3); cross-half prefetch at 34/35
          if (r < 34) loadB(Hf[(r + 2) % 3], ch * 36 + r + 2);
          else if (ch == 0) loadB(Hf[(r + 2) % 3], 36 + (r - 34));
          // A fragments for this round (2 m-tiles)
          bf16x8 af[2];
#pragma unroll
          for (int mt = 0; mt < 2; ++mt)
            af[mt] = *(const bf16x8*)&lds_a[abase +
                     (((mt * 2 + kh) * PWw + kw) * RSTR + kg * 16)];
          __builtin_amdgcn_s_setprio(1);
#pragma unroll
          for (int mt = 0; mt < 2; ++mt)
#pragma unroll
            for (int g = 0; g < 2; ++g)
              acc[mt][g] = __builtin_amdgcn_mfma_f32_32x32x16_bf16(
                  af[mt], Hf[r % 3][g], acc[mt][g], 0, 0, 0);
          __builtin_amdgcn_s_setprio(0);
        }
      }
    }
  }

  // ---- epilogue: C/D 32x32 map col=lane&31 (co), row=(reg&3)+8*(reg>>2)+4*kk ----
  float* ob = out + (size_t)b * HO * WO * CO;
  const int co0 = wc * 64 + (lane & 31);
#pragma unroll
  for (int mt = 0; mt < 2; ++mt) {
#pragma unroll
    for (int g = 0; g < 2; ++g) {
      const int co = co0 + g * 32;
#pragma unroll
      for (int reg = 0; reg < 16; ++reg) {
        const int M = (reg & 3) + 8 * (reg >> 2) + 4 * kk;
        const int hp = h0 + wr * 4 + mt * 2 + (M >> 4);
        const int wp = w0 + (M & 15);
        if (hp < HO && wp < WO)
          ob[((size_t)hp * WO + wp) * CO + co] = acc[mt][g][reg];
      }
    }
  }
}

extern "C" void kernel_launch(void* const* d_in, const int* in_sizes, int n_in,
                              void* d_out, int out_size, void* d_ws, size_t ws_size,
                              hipStream_t stream) {
  const float* X = (const float*)d_in[0];
  const float* Kf = (const float*)d_in[1];
  float* out = (float*)d_out;
  size_t need = (size_t)NB * 9 * CI * CO * sizeof(unsigned short);  // 9.4 MB
  if (d_ws != nullptr && ws_size >= need) {
    unsigned short* ktr = (unsigned short*)d_ws;
    prep_kt<<<dim3(NB * 9), 256, 0, stream>>>(Kf, ktr);
    conv_main<<<dim3(2048), 512, 0, stream>>>(X, ktr, out);
  } else {
    int total = NB * HO * WO * CO;
    conv_naive<<<(total + 255) / 256, 256, 0, stream>>>(X, Kf, out);
  }
}